// Round 3
// baseline (165.346 us; speedup 1.0000x reference)
//
#include <hip/hip_runtime.h>
#include <hip/hip_bf16.h>

// Problem constants
#define B_  64
#define N_  4096
#define F_  64
#define H1_ 128
#define H2_ 128

#define GRID_  512          // 2 blocks/CU
#define ITERS_ 4            // 2048 tiles of 128 rows / 512 blocks

typedef __attribute__((ext_vector_type(8))) short bf16x8;   // 8 bf16 (4 VGPRs)
typedef __attribute__((ext_vector_type(4))) float f32x4;    // MFMA accumulator

__device__ __forceinline__ unsigned short f2bf(float f) {
    union { float f; unsigned int u; } v; v.f = f;
    unsigned int u = v.u;
    return (unsigned short)((u + 0x7fffu + ((u >> 16) & 1u)) >> 16);  // RNE
}

__device__ __forceinline__ bf16x8 pack8(float4 a, float4 b) {
    bf16x8 r;
    r[0] = (short)f2bf(a.x); r[1] = (short)f2bf(a.y);
    r[2] = (short)f2bf(a.z); r[3] = (short)f2bf(a.w);
    r[4] = (short)f2bf(b.x); r[5] = (short)f2bf(b.y);
    r[6] = (short)f2bf(b.z); r[7] = (short)f2bf(b.w);
    return r;
}

// ---------------------------------------------------------------------------
// Fused MLP -> exp(masked logits) -> per-batch sum (atomic).
// Block = 256 threads (4 waves). Each wave owns 32 rows per tile iteration.
// Barrier-free main loop: W1 in registers, X direct global->reg, H1 through a
// per-wave LDS slice (lgkmcnt only), W2 read-only in LDS.
// Layer 1 uses SWAPPED operands: C1 = mfma(A=W1^T[h][f], B=X^T[f][row])
//   -> lane holds col=row(lr), row=h(lg*4+j)  => H1 written packed b64.
// Layer 2 standard: C2 = mfma(A=H1[row][h1], B=W2[h1][h2]).
// ---------------------------------------------------------------------------
__global__ __launch_bounds__(256, 2) void mlp_kernel(
    const float* __restrict__ x,
    const int*   __restrict__ mask,
    const float* __restrict__ W1,    // [F=64][H1=128] f32
    const float* __restrict__ b1,
    const float* __restrict__ W2,    // [H1=128][H2=128] f32
    const float* __restrict__ b2,
    const float* __restrict__ W3,
    const float* __restrict__ b3,
    float* __restrict__ eout,        // exp(tns) per row
    float* __restrict__ sums)        // [B] batch exp-sums (pre-zeroed)
{
    __shared__ unsigned short W2s[128][136];   // [h2][h1], +8 pad  (34816 B)
    __shared__ unsigned short H1s[128][136];   // 4 wave slices of [32][136]
    __shared__ float b1s[128];

    const int t    = threadIdx.x;
    const int wave = t >> 6;
    const int lane = t & 63;
    const int lr   = lane & 15;
    const int lg   = lane >> 4;

    // ---- stage W2 (transposed) + b1 into LDS, once ----
    #pragma unroll
    for (int i = 0; i < 16; ++i) {
        int idx4 = i * 256 + t;              // 0..4095 float4s of W2
        int h1 = idx4 >> 5;
        int h2 = (idx4 & 31) << 2;
        float4 v = ((const float4*)W2)[idx4];
        W2s[h2 + 0][h1] = f2bf(v.x);
        W2s[h2 + 1][h1] = f2bf(v.y);
        W2s[h2 + 2][h1] = f2bf(v.z);
        W2s[h2 + 3][h1] = f2bf(v.w);
    }
    if (t < 32) *(float4*)&b1s[t * 4] = ((const float4*)b1)[t];

    // ---- W1 A-fragments into registers (16 frags = 64 VGPR) ----
    bf16x8 w1f[8][2];                        // [h-block][k-step]
    #pragma unroll
    for (int hb = 0; hb < 8; ++hb) {
        #pragma unroll
        for (int ks = 0; ks < 2; ++ks) {
            bf16x8 r;
            #pragma unroll
            for (int i = 0; i < 8; ++i)
                r[i] = (short)f2bf(W1[(ks * 32 + lg * 8 + i) * 128 + hb * 16 + lr]);
            w1f[hb][ks] = r;
        }
    }
    // per-lane epilogue constants (col = hb*16 + lr)
    float b2v[8], w3v[8];
    #pragma unroll
    for (int hb = 0; hb < 8; ++hb) {
        b2v[hb] = b2[hb * 16 + lr];
        w3v[hb] = W3[hb * 16 + lr];
    }
    const float b3v = b3[0];
    __syncthreads();   // the only block-wide barrier

    unsigned short (*H1w)[136] = (unsigned short (*)[136])&H1s[wave * 32];

    // ---- prefetch X for first tile ----
    float4 xr[2][2][2];                      // [nb][ks][half]
    {
        const int rb0 = blockIdx.x * 128 + wave * 32;
        #pragma unroll
        for (int nb = 0; nb < 2; ++nb)
            #pragma unroll
            for (int ks = 0; ks < 2; ++ks) {
                const float4* p = (const float4*)(x + (size_t)(rb0 + nb * 16 + lr) * 64 + ks * 32 + lg * 8);
                xr[nb][ks][0] = p[0];
                xr[nb][ks][1] = p[1];
            }
    }

    #pragma unroll
    for (int it = 0; it < ITERS_; ++it) {
        const int tile = it * GRID_ + blockIdx.x;
        const int rb   = tile * 128 + wave * 32;

        // convert current X to bf16 B-fragments (frees xr for prefetch)
        bf16x8 xb[2][2];
        #pragma unroll
        for (int nb = 0; nb < 2; ++nb)
            #pragma unroll
            for (int ks = 0; ks < 2; ++ks)
                xb[nb][ks] = pack8(xr[nb][ks][0], xr[nb][ks][1]);

        // issue next tile's loads early (hide HBM under L1+L2 compute)
        if (it < ITERS_ - 1) {
            const int rbn = rb + GRID_ * 128;
            #pragma unroll
            for (int nb = 0; nb < 2; ++nb)
                #pragma unroll
                for (int ks = 0; ks < 2; ++ks) {
                    const float4* p = (const float4*)(x + (size_t)(rbn + nb * 16 + lr) * 64 + ks * 32 + lg * 8);
                    xr[nb][ks][0] = p[0];
                    xr[nb][ks][1] = p[1];
                }
        }

        // ---- layer 1: C1[h=128][row=32], acc init = b1 ----
        f32x4 acc[8][2];                     // [hb][nb]
        #pragma unroll
        for (int hb = 0; hb < 8; ++hb) {
            f32x4 bi = *(const f32x4*)&b1s[hb * 16 + lg * 4];
            acc[hb][0] = bi;
            acc[hb][1] = bi;
        }
        #pragma unroll
        for (int ks = 0; ks < 2; ++ks)
            #pragma unroll
            for (int hb = 0; hb < 8; ++hb) {
                acc[hb][0] = __builtin_amdgcn_mfma_f32_16x16x32_bf16(w1f[hb][ks], xb[0][ks], acc[hb][0], 0, 0, 0);
                acc[hb][1] = __builtin_amdgcn_mfma_f32_16x16x32_bf16(w1f[hb][ks], xb[1][ks], acc[hb][1], 0, 0, 0);
            }

        // ---- relu -> bf16 -> per-wave H1 slice (packed b64 writes) ----
        #pragma unroll
        for (int nb = 0; nb < 2; ++nb)
            #pragma unroll
            for (int hb = 0; hb < 8; ++hb) {
                f32x4 v = acc[hb][nb];
                float v0 = fmaxf(v[0], 0.0f), v1 = fmaxf(v[1], 0.0f);
                float v2 = fmaxf(v[2], 0.0f), v3 = fmaxf(v[3], 0.0f);
                unsigned int lo = (unsigned)f2bf(v0) | ((unsigned)f2bf(v1) << 16);
                unsigned int hi = (unsigned)f2bf(v2) | ((unsigned)f2bf(v3) << 16);
                *(uint2*)&H1w[nb * 16 + lr][hb * 16 + lg * 4] = make_uint2(lo, hi);
            }
        // same-wave write->read ordering (no barrier needed: per-wave slice)
        asm volatile("s_waitcnt lgkmcnt(0)" ::: "memory");

        // ---- layer 2: C2[row=32][h2=128], acc init = b2 ----
        bf16x8 a2[2][4];                     // [mb][ks]
        #pragma unroll
        for (int mb = 0; mb < 2; ++mb)
            #pragma unroll
            for (int ks = 0; ks < 4; ++ks)
                a2[mb][ks] = *(const bf16x8*)&H1w[mb * 16 + lr][ks * 32 + lg * 8];

        f32x4 c2[2][8];                      // [mb][hb]
        #pragma unroll
        for (int mb = 0; mb < 2; ++mb)
            #pragma unroll
            for (int hb = 0; hb < 8; ++hb) {
                f32x4 ci = {b2v[hb], b2v[hb], b2v[hb], b2v[hb]};
                c2[mb][hb] = ci;
            }
        #pragma unroll
        for (int ks = 0; ks < 4; ++ks)
            #pragma unroll
            for (int hb = 0; hb < 8; ++hb) {
                bf16x8 bfrag = *(const bf16x8*)&W2s[hb * 16 + lr][ks * 32 + lg * 8];
                c2[0][hb] = __builtin_amdgcn_mfma_f32_16x16x32_bf16(a2[0][ks], bfrag, c2[0][hb], 0, 0, 0);
                c2[1][hb] = __builtin_amdgcn_mfma_f32_16x16x32_bf16(a2[1][ks], bfrag, c2[1][hb], 0, 0, 0);
            }

        // ---- layer 3 + mask + exp + batch-sum ----
        float p[2][4];
        #pragma unroll
        for (int mb = 0; mb < 2; ++mb)
            #pragma unroll
            for (int j = 0; j < 4; ++j) {
                float s = 0.0f;
                #pragma unroll
                for (int hb = 0; hb < 8; ++hb) {
                    float v = fmaxf(c2[mb][hb][j], 0.0f);
                    s += v * w3v[hb];
                }
                p[mb][j] = s;
            }
        #pragma unroll
        for (int m = 1; m < 16; m <<= 1)
            #pragma unroll
            for (int mb = 0; mb < 2; ++mb)
                #pragma unroll
                for (int j = 0; j < 4; ++j)
                    p[mb][j] += __shfl_xor(p[mb][j], m, 64);

        float ssum = 0.0f;
        if (lr == 0) {                        // 4 lanes/wave own 8 rows each
            #pragma unroll
            for (int mb = 0; mb < 2; ++mb) {
                int r0 = rb + mb * 16 + lg * 4;
                int4 mk = *(const int4*)&mask[r0];
                float4 ev;
                ev.x = mk.x ? expf(p[mb][0] + b3v) : 0.0f;
                ev.y = mk.y ? expf(p[mb][1] + b3v) : 0.0f;
                ev.z = mk.z ? expf(p[mb][2] + b3v) : 0.0f;
                ev.w = mk.w ? expf(p[mb][3] + b3v) : 0.0f;
                *(float4*)&eout[r0] = ev;
                ssum += ev.x + ev.y + ev.z + ev.w;
            }
        }
        ssum += __shfl_xor(ssum, 16, 64);
        ssum += __shfl_xor(ssum, 32, 64);
        if (lane == 0) atomicAdd(&sums[tile >> 5], ssum);   // 32 tiles per batch
    }
}

// ---------------------------------------------------------------------------
// out = e / sums[batch]
// ---------------------------------------------------------------------------
__global__ __launch_bounds__(256) void norm_kernel(
    const float* __restrict__ e, const float* __restrict__ sums,
    float* __restrict__ out)
{
    int i4 = blockIdx.x * 256 + threadIdx.x;       // 65536 float4s
    float4 v = ((const float4*)e)[i4];
    float inv = 1.0f / sums[i4 >> 10];             // 1024 float4 per batch
    v.x *= inv; v.y *= inv; v.z *= inv; v.w *= inv;
    ((float4*)out)[i4] = v;
}

// ---------------------------------------------------------------------------
extern "C" void kernel_launch(void* const* d_in, const int* in_sizes, int n_in,
                              void* d_out, int out_size, void* d_ws, size_t ws_size,
                              hipStream_t stream)
{
    const float* x    = (const float*)d_in[0];
    const int*   mask = (const int*)d_in[1];
    const float* W1   = (const float*)d_in[2];
    const float* b1   = (const float*)d_in[3];
    const float* W2   = (const float*)d_in[4];
    const float* b2   = (const float*)d_in[5];
    const float* W3   = (const float*)d_in[6];
    const float* b3   = (const float*)d_in[7];
    float* out = (float*)d_out;

    float* sums = (float*)d_ws;                          // 64 floats
    float* eout = (float*)((char*)d_ws + 1024);          // 1 MB

    hipMemsetAsync(sums, 0, B_ * sizeof(float), stream);
    mlp_kernel<<<GRID_, 256, 0, stream>>>(x, mask, W1, b1, W2, b2, W3, b3, eout, sums);
    norm_kernel<<<(B_ * N_ / 4) / 256, 256, 0, stream>>>(eout, sums, out);
}

// Round 4
// 132.188 us; speedup vs baseline: 1.2508x; 1.2508x over previous
//
#include <hip/hip_runtime.h>
#include <hip/hip_bf16.h>

// Problem constants
#define B_  64
#define N_  4096
#define F_  64
#define H1_ 128
#define H2_ 128

#define GRID_  512          // 2 blocks/CU (persistent)
#define ITERS_ 4            // each block: 4 consecutive tiles of 128 rows

typedef __attribute__((ext_vector_type(8))) short bf16x8;   // 8 bf16 (4 VGPRs)
typedef __attribute__((ext_vector_type(4))) float f32x4;    // MFMA accumulator

__device__ __forceinline__ unsigned short f2bf(float f) {
    union { float f; unsigned int u; } v; v.f = f;
    unsigned int u = v.u;
    return (unsigned short)((u + 0x7fffu + ((u >> 16) & 1u)) >> 16);  // RNE
}

__device__ __forceinline__ bf16x8 pack8(float4 a, float4 b) {
    bf16x8 r;
    r[0] = (short)f2bf(a.x); r[1] = (short)f2bf(a.y);
    r[2] = (short)f2bf(a.z); r[3] = (short)f2bf(a.w);
    r[4] = (short)f2bf(b.x); r[5] = (short)f2bf(b.y);
    r[6] = (short)f2bf(b.z); r[7] = (short)f2bf(b.w);
    return r;
}

// ---------------------------------------------------------------------------
// Fused MLP -> exp(masked logits) -> per-batch sum.
// Block = 256 threads (4 waves), each wave owns 32 rows per tile iteration.
// Barrier-free main loop: W1 in registers, X direct global->reg (prefetched
// one tile ahead), H1 through a per-wave LDS slice (lgkmcnt only), W2 in LDS.
// tile = blockIdx*4 + it  => whole block stays in ONE batch (blockIdx>>3);
// batch sum accumulated in-register, ONE atomicAdd per wave after the loop
// (the per-iteration same-address atomic storm was the R2 3x regression).
// ---------------------------------------------------------------------------
__global__ __launch_bounds__(256, 2) void mlp_kernel(
    const float* __restrict__ x,
    const int*   __restrict__ mask,
    const float* __restrict__ W1,    // [F=64][H1=128] f32
    const float* __restrict__ b1,
    const float* __restrict__ W2,    // [H1=128][H2=128] f32
    const float* __restrict__ b2,
    const float* __restrict__ W3,
    const float* __restrict__ b3,
    float* __restrict__ eout,        // exp(tns) per row
    float* __restrict__ sums)        // [B] batch exp-sums (pre-zeroed)
{
    __shared__ unsigned short W2s[128][136];   // [h2][h1], +8 pad  (34816 B)
    __shared__ unsigned short H1s[128][136];   // 4 wave slices of [32][136]
    __shared__ float b1s[128];

    const int t    = threadIdx.x;
    const int wave = t >> 6;
    const int lane = t & 63;
    const int lr   = lane & 15;
    const int lg   = lane >> 4;

    // ---- stage W2 (transposed) + b1 into LDS, once ----
    #pragma unroll
    for (int i = 0; i < 16; ++i) {
        int idx4 = i * 256 + t;              // 0..4095 float4s of W2
        int h1 = idx4 >> 5;
        int h2 = (idx4 & 31) << 2;
        float4 v = ((const float4*)W2)[idx4];
        W2s[h2 + 0][h1] = f2bf(v.x);
        W2s[h2 + 1][h1] = f2bf(v.y);
        W2s[h2 + 2][h1] = f2bf(v.z);
        W2s[h2 + 3][h1] = f2bf(v.w);
    }
    if (t < 32) *(float4*)&b1s[t * 4] = ((const float4*)b1)[t];

    // ---- W1 A-fragments into registers (16 frags = 64 VGPR) ----
    bf16x8 w1f[8][2];                        // [h-block][k-step]
    #pragma unroll
    for (int hb = 0; hb < 8; ++hb) {
        #pragma unroll
        for (int ks = 0; ks < 2; ++ks) {
            bf16x8 r;
            #pragma unroll
            for (int i = 0; i < 8; ++i)
                r[i] = (short)f2bf(W1[(ks * 32 + lg * 8 + i) * 128 + hb * 16 + lr]);
            w1f[hb][ks] = r;
        }
    }
    // per-lane epilogue constants (col = hb*16 + lr)
    float b2v[8], w3v[8];
    #pragma unroll
    for (int hb = 0; hb < 8; ++hb) {
        b2v[hb] = b2[hb * 16 + lr];
        w3v[hb] = W3[hb * 16 + lr];
    }
    const float b3v = b3[0];
    __syncthreads();   // the only block-wide barrier

    unsigned short (*H1w)[136] = (unsigned short (*)[136])&H1s[wave * 32];

    // ---- prefetch X for first tile (tile = blockIdx*4) ----
    float4 xr[2][2][2];                      // [nb][ks][half]
    {
        const int rb0 = (blockIdx.x * ITERS_) * 128 + wave * 32;
        #pragma unroll
        for (int nb = 0; nb < 2; ++nb)
            #pragma unroll
            for (int ks = 0; ks < 2; ++ks) {
                const float4* p = (const float4*)(x + (size_t)(rb0 + nb * 16 + lr) * 64 + ks * 32 + lg * 8);
                xr[nb][ks][0] = p[0];
                xr[nb][ks][1] = p[1];
            }
    }

    float ssum = 0.0f;                       // accumulated across iterations

    #pragma unroll
    for (int it = 0; it < ITERS_; ++it) {
        const int tile = blockIdx.x * ITERS_ + it;   // consecutive tiles
        const int rb   = tile * 128 + wave * 32;

        // mask for this iteration's epilogue rows: issue EARLY (lr==0 lanes)
        int4 mk0, mk1;
        if (lr == 0) {
            mk0 = *(const int4*)&mask[rb + lg * 4];
            mk1 = *(const int4*)&mask[rb + 16 + lg * 4];
        }

        // convert current X to bf16 B-fragments (frees xr for prefetch)
        bf16x8 xb[2][2];
        #pragma unroll
        for (int nb = 0; nb < 2; ++nb)
            #pragma unroll
            for (int ks = 0; ks < 2; ++ks)
                xb[nb][ks] = pack8(xr[nb][ks][0], xr[nb][ks][1]);

        // issue next tile's loads (consumed next iteration)
        if (it < ITERS_ - 1) {
            const int rbn = rb + 128;
            #pragma unroll
            for (int nb = 0; nb < 2; ++nb)
                #pragma unroll
                for (int ks = 0; ks < 2; ++ks) {
                    const float4* p = (const float4*)(x + (size_t)(rbn + nb * 16 + lr) * 64 + ks * 32 + lg * 8);
                    xr[nb][ks][0] = p[0];
                    xr[nb][ks][1] = p[1];
                }
        }

        // ---- layer 1: C1[h=128][row=32], acc init = b1 ----
        f32x4 acc[8][2];                     // [hb][nb]
        #pragma unroll
        for (int hb = 0; hb < 8; ++hb) {
            f32x4 bi = *(const f32x4*)&b1s[hb * 16 + lg * 4];
            acc[hb][0] = bi;
            acc[hb][1] = bi;
        }
        #pragma unroll
        for (int ks = 0; ks < 2; ++ks)
            #pragma unroll
            for (int hb = 0; hb < 8; ++hb) {
                acc[hb][0] = __builtin_amdgcn_mfma_f32_16x16x32_bf16(w1f[hb][ks], xb[0][ks], acc[hb][0], 0, 0, 0);
                acc[hb][1] = __builtin_amdgcn_mfma_f32_16x16x32_bf16(w1f[hb][ks], xb[1][ks], acc[hb][1], 0, 0, 0);
            }

        // ---- relu -> bf16 -> per-wave H1 slice (packed b64 writes) ----
        #pragma unroll
        for (int nb = 0; nb < 2; ++nb)
            #pragma unroll
            for (int hb = 0; hb < 8; ++hb) {
                f32x4 v = acc[hb][nb];
                float v0 = fmaxf(v[0], 0.0f), v1 = fmaxf(v[1], 0.0f);
                float v2 = fmaxf(v[2], 0.0f), v3 = fmaxf(v[3], 0.0f);
                unsigned int lo = (unsigned)f2bf(v0) | ((unsigned)f2bf(v1) << 16);
                unsigned int hi = (unsigned)f2bf(v2) | ((unsigned)f2bf(v3) << 16);
                *(uint2*)&H1w[nb * 16 + lr][hb * 16 + lg * 4] = make_uint2(lo, hi);
            }
        // same-wave write->read ordering (no barrier needed: per-wave slice)
        asm volatile("s_waitcnt lgkmcnt(0)" ::: "memory");

        // ---- layer 2: C2[row=32][h2=128], acc init = b2 ----
        bf16x8 a2[2][4];                     // [mb][ks]
        #pragma unroll
        for (int mb = 0; mb < 2; ++mb)
            #pragma unroll
            for (int ks = 0; ks < 4; ++ks)
                a2[mb][ks] = *(const bf16x8*)&H1w[mb * 16 + lr][ks * 32 + lg * 8];

        f32x4 c2[2][8];                      // [mb][hb]
        #pragma unroll
        for (int mb = 0; mb < 2; ++mb)
            #pragma unroll
            for (int hb = 0; hb < 8; ++hb) {
                f32x4 ci = {b2v[hb], b2v[hb], b2v[hb], b2v[hb]};
                c2[mb][hb] = ci;
            }
        #pragma unroll
        for (int ks = 0; ks < 4; ++ks)
            #pragma unroll
            for (int hb = 0; hb < 8; ++hb) {
                bf16x8 bfrag = *(const bf16x8*)&W2s[hb * 16 + lr][ks * 32 + lg * 8];
                c2[0][hb] = __builtin_amdgcn_mfma_f32_16x16x32_bf16(a2[0][ks], bfrag, c2[0][hb], 0, 0, 0);
                c2[1][hb] = __builtin_amdgcn_mfma_f32_16x16x32_bf16(a2[1][ks], bfrag, c2[1][hb], 0, 0, 0);
            }

        // ---- layer 3 + mask + exp (batch-sum accumulated in register) ----
        float p[2][4];
        #pragma unroll
        for (int mb = 0; mb < 2; ++mb)
            #pragma unroll
            for (int j = 0; j < 4; ++j) {
                float s = 0.0f;
                #pragma unroll
                for (int hb = 0; hb < 8; ++hb) {
                    float v = fmaxf(c2[mb][hb][j], 0.0f);
                    s += v * w3v[hb];
                }
                p[mb][j] = s;
            }
        #pragma unroll
        for (int m = 1; m < 16; m <<= 1)
            #pragma unroll
            for (int mb = 0; mb < 2; ++mb)
                #pragma unroll
                for (int j = 0; j < 4; ++j)
                    p[mb][j] += __shfl_xor(p[mb][j], m, 64);

        if (lr == 0) {                        // 4 lanes/wave own 8 rows each
            int r0 = rb + lg * 4;
            float4 ev0, ev1;
            ev0.x = mk0.x ? expf(p[0][0] + b3v) : 0.0f;
            ev0.y = mk0.y ? expf(p[0][1] + b3v) : 0.0f;
            ev0.z = mk0.z ? expf(p[0][2] + b3v) : 0.0f;
            ev0.w = mk0.w ? expf(p[0][3] + b3v) : 0.0f;
            ev1.x = mk1.x ? expf(p[1][0] + b3v) : 0.0f;
            ev1.y = mk1.y ? expf(p[1][1] + b3v) : 0.0f;
            ev1.z = mk1.z ? expf(p[1][2] + b3v) : 0.0f;
            ev1.w = mk1.w ? expf(p[1][3] + b3v) : 0.0f;
            *(float4*)&eout[r0]      = ev0;
            *(float4*)&eout[r0 + 16] = ev1;
            ssum += ev0.x + ev0.y + ev0.z + ev0.w
                  + ev1.x + ev1.y + ev1.z + ev1.w;
        }
    }

    // ---- single batch-sum atomic per wave (batch constant per block) ----
    ssum += __shfl_xor(ssum, 16, 64);
    ssum += __shfl_xor(ssum, 32, 64);
    if (lane == 0) atomicAdd(&sums[blockIdx.x >> 3], ssum);
}

// ---------------------------------------------------------------------------
// out = e / sums[batch]
// ---------------------------------------------------------------------------
__global__ __launch_bounds__(256) void norm_kernel(
    const float* __restrict__ e, const float* __restrict__ sums,
    float* __restrict__ out)
{
    int i4 = blockIdx.x * 256 + threadIdx.x;       // 65536 float4s
    float4 v = ((const float4*)e)[i4];
    float inv = 1.0f / sums[i4 >> 10];             // 1024 float4 per batch
    v.x *= inv; v.y *= inv; v.z *= inv; v.w *= inv;
    ((float4*)out)[i4] = v;
}

// ---------------------------------------------------------------------------
extern "C" void kernel_launch(void* const* d_in, const int* in_sizes, int n_in,
                              void* d_out, int out_size, void* d_ws, size_t ws_size,
                              hipStream_t stream)
{
    const float* x    = (const float*)d_in[0];
    const int*   mask = (const int*)d_in[1];
    const float* W1   = (const float*)d_in[2];
    const float* b1   = (const float*)d_in[3];
    const float* W2   = (const float*)d_in[4];
    const float* b2   = (const float*)d_in[5];
    const float* W3   = (const float*)d_in[6];
    const float* b3   = (const float*)d_in[7];
    float* out = (float*)d_out;

    float* sums = (float*)d_ws;                          // 64 floats
    float* eout = (float*)((char*)d_ws + 1024);          // 1 MB

    hipMemsetAsync(sums, 0, B_ * sizeof(float), stream);
    mlp_kernel<<<GRID_, 256, 0, stream>>>(x, mask, W1, b1, W2, b2, W3, b3, eout, sums);
    norm_kernel<<<(B_ * N_ / 4) / 256, 256, 0, stream>>>(eout, sums, out);
}